// Round 1
// baseline (3785.586 us; speedup 1.0000x reference)
//
#include <hip/hip_runtime.h>
#include <cstdint>
#include <cstddef>

#define TT 256
#define BB 512
#define DD 512
#define HH 512
#define G3 1536  // 3*H

typedef __attribute__((ext_vector_type(4))) float  f32x4;
typedef __attribute__((ext_vector_type(8))) short  s16x8;   // 8 bf16 (MFMA frag)
typedef __attribute__((ext_vector_type(8))) ushort u16x8;
typedef __attribute__((ext_vector_type(4))) ushort u16x4;

__device__ __forceinline__ ushort f2bf(float f) {
    union { float f; uint32_t u; } a; a.f = f;
    uint32_t u = a.u;
    u += 0x7FFFu + ((u >> 16) & 1u);   // round-to-nearest-even
    return (ushort)(u >> 16);
}
__device__ __forceinline__ float bf2f(ushort h) {
    union { uint32_t u; float f; } a; a.u = ((uint32_t)h) << 16;
    return a.f;
}
__device__ __forceinline__ float sigmoidf_(float x) {
    return 1.0f / (1.0f + __expf(-x));
}

// ---------------- fp32 -> bf16 conversion (8 elems/thread) ----------------
__global__ __launch_bounds__(256) void conv_f32_bf16(const float* __restrict__ in,
                                                     ushort* __restrict__ out, int n8) {
    int i = blockIdx.x * 256 + threadIdx.x;
    if (i >= n8) return;
    const float4* p = (const float4*)in + (size_t)i * 2;
    float4 a = p[0], b = p[1];
    u16x8 o;
    o[0] = f2bf(a.x); o[1] = f2bf(a.y); o[2] = f2bf(a.z); o[3] = f2bf(a.w);
    o[4] = f2bf(b.x); o[5] = f2bf(b.y); o[6] = f2bf(b.z); o[7] = f2bf(b.w);
    ((u16x8*)out)[i] = o;
}

// ---------------- float4 copy ----------------
__global__ __launch_bounds__(256) void copy_f32(const float* __restrict__ in,
                                                float* __restrict__ out, int n4) {
    int i = blockIdx.x * 256 + threadIdx.x;
    if (i < n4) ((float4*)out)[i] = ((const float4*)in)[i];
}

// ---------------- phase-1 GEMM: xp[M][N] = A[M][K] * B[N][K]^T + bias[N] ----------------
// A = x (bf16), B = w_ih (bf16, row-major N x K), out fp32 (or bf16 fallback).
// 128x128 tile, BK=64, 256 threads (2x2 waves of 64x64).
template<bool XPBF>
__global__ __launch_bounds__(256) void gemm_xp(const ushort* __restrict__ A,
                                               const ushort* __restrict__ Bw,
                                               const float* __restrict__ bias,
                                               void* __restrict__ Cv) {
    __shared__ ushort As[128][72];   // +8 pad: conflict-free b128 r/w
    __shared__ ushort Bs[128][72];
    const int tid = threadIdx.x;
    const int m0 = blockIdx.y * 128, n0 = blockIdx.x * 128;
    const int wv = tid >> 6, l = tid & 63, quad = l >> 4, ln = l & 15;
    const int wm = (wv & 1) * 64, wn = (wv >> 1) * 64;

    f32x4 zero = {0.f, 0.f, 0.f, 0.f};
    f32x4 acc[4][4];
#pragma unroll
    for (int mt = 0; mt < 4; ++mt)
#pragma unroll
        for (int nt = 0; nt < 4; ++nt) acc[mt][nt] = zero;

    for (int k0 = 0; k0 < DD; k0 += 64) {
        __syncthreads();
#pragma unroll
        for (int i = 0; i < 4; ++i) {
            int c = tid + i * 256;            // 1024 chunks of 16B
            int row = c >> 3, col = (c & 7) * 8;
            *(u16x8*)&As[row][col] = *(const u16x8*)&A[(size_t)(m0 + row) * DD + k0 + col];
            *(u16x8*)&Bs[row][col] = *(const u16x8*)&Bw[(size_t)(n0 + row) * DD + k0 + col];
        }
        __syncthreads();
#pragma unroll
        for (int ks = 0; ks < 64; ks += 32) {
            s16x8 af[4], bf[4];
#pragma unroll
            for (int t = 0; t < 4; ++t) af[t] = *(const s16x8*)&As[wm + t * 16 + ln][ks + quad * 8];
#pragma unroll
            for (int t = 0; t < 4; ++t) bf[t] = *(const s16x8*)&Bs[wn + t * 16 + ln][ks + quad * 8];
#pragma unroll
            for (int mt = 0; mt < 4; ++mt)
#pragma unroll
                for (int nt = 0; nt < 4; ++nt)
                    acc[mt][nt] = __builtin_amdgcn_mfma_f32_16x16x32_bf16(af[mt], bf[nt], acc[mt][nt], 0, 0, 0);
        }
    }
#pragma unroll
    for (int mt = 0; mt < 4; ++mt) {
#pragma unroll
        for (int nt = 0; nt < 4; ++nt) {
            int col = n0 + wn + nt * 16 + ln;
            float bsv = bias[col];
            int row = m0 + wm + mt * 16 + quad * 4;
#pragma unroll
            for (int i = 0; i < 4; ++i) {
                float v = acc[mt][nt][i] + bsv;
                if constexpr (XPBF) ((ushort*)Cv)[(size_t)(row + i) * G3 + col] = f2bf(v);
                else                ((float*)Cv)[(size_t)(row + i) * G3 + col]  = v;
            }
        }
    }
}

// ---------------- one GRU step ----------------
// grid (16 j-tiles, 16 b-tiles), 256 threads. b-tile=32, j-tile=32.
// gh tile (32 x 96) = h_masked(32x512,bf16 LDS) @ w_hh^T (bf16 direct-from-global frags)
template<bool XPBF>
__global__ __launch_bounds__(256) void gru_step(const float* __restrict__ h_cur,
                                                float* __restrict__ h_nxt,
                                                const ushort* __restrict__ whh,
                                                const void* __restrict__ xp_t,
                                                const float* __restrict__ mask_t,
                                                const float* __restrict__ b_hh,
                                                float* __restrict__ out_t) {
    __shared__ ushort h_s[32][520];   // 32x512 bf16, +8 pad (33,280 B)
    __shared__ float  gh_s[32][100];  // 32x96 fp32, +4 pad (12,800 B)
    const int tid = threadIdx.x;
    const int b0 = blockIdx.y * 32, j0 = blockIdx.x * 32;

    // stage h (fp32 -> mask -> bf16 -> LDS): 32x512 = 16384 floats, 64/thread
#pragma unroll
    for (int i = 0; i < 16; ++i) {
        int c = tid + i * 256;
        int row = c >> 7, col = (c & 127) * 4;
        float4 v = *(const float4*)&h_cur[(b0 + row) * HH + col];
        float m = mask_t[b0 + row];
        u16x4 o;
        o[0] = f2bf(v.x * m); o[1] = f2bf(v.y * m);
        o[2] = f2bf(v.z * m); o[3] = f2bf(v.w * m);
        *(u16x4*)&h_s[row][col] = o;
    }
    __syncthreads();

    const int wv = tid >> 6, l = tid & 63, quad = l >> 4, ln = l & 15;
    const int m_off  = (wv >> 1) * 16;   // which 16 rows of the 32-row b-tile
    const int n_base = (wv & 1) * 48;    // which 48 of the 96 local cols

    // per-lane w_hh row pointers for the 3 n-tiles (local col layout: [3 gates][32 j])
    const ushort* wp[3];
#pragma unroll
    for (int nt = 0; nt < 3; ++nt) {
        int cb = n_base + nt * 16;       // local col base, within one gate block
        int g  = cb >> 5;
        int jj = (cb & 31) + ln;
        wp[nt] = whh + (size_t)(g * HH + j0 + jj) * HH;
    }

    f32x4 zero = {0.f, 0.f, 0.f, 0.f};
    f32x4 acc0 = zero, acc1 = zero, acc2 = zero;
#pragma unroll
    for (int k0 = 0; k0 < HH; k0 += 32) {
        int ko = k0 + quad * 8;
        s16x8 a  = *(const s16x8*)&h_s[m_off + ln][ko];
        s16x8 w0 = *(const s16x8*)&wp[0][ko];
        s16x8 w1 = *(const s16x8*)&wp[1][ko];
        s16x8 w2 = *(const s16x8*)&wp[2][ko];
        acc0 = __builtin_amdgcn_mfma_f32_16x16x32_bf16(a, w0, acc0, 0, 0, 0);
        acc1 = __builtin_amdgcn_mfma_f32_16x16x32_bf16(a, w1, acc1, 0, 0, 0);
        acc2 = __builtin_amdgcn_mfma_f32_16x16x32_bf16(a, w2, acc2, 0, 0, 0);
    }
    // C layout: row(m)=quad*4+i, col(n)=ln
#pragma unroll
    for (int i = 0; i < 4; ++i) {
        gh_s[m_off + quad * 4 + i][n_base + ln]      = acc0[i];
        gh_s[m_off + quad * 4 + i][n_base + 16 + ln] = acc1[i];
        gh_s[m_off + quad * 4 + i][n_base + 32 + ln] = acc2[i];
    }
    __syncthreads();

    // gate combine: thread -> (b_loc = tid>>3, 4 consecutive j at (tid&7)*4)
    const int bl = tid >> 3;
    const int jl = (tid & 7) * 4;
    const int b  = b0 + bl;
    const int jg = j0 + jl;

    float4 hr = *(const float4*)&gh_s[bl][jl];
    float4 hz = *(const float4*)&gh_s[bl][32 + jl];
    float4 hn = *(const float4*)&gh_s[bl][64 + jl];

    float4 xr, xz, xn;
    if constexpr (XPBF) {
        const ushort* xp = (const ushort*)xp_t + (size_t)b * G3;
        u16x4 a0 = *(const u16x4*)&xp[jg];
        u16x4 a1 = *(const u16x4*)&xp[512 + jg];
        u16x4 a2 = *(const u16x4*)&xp[1024 + jg];
        xr.x = bf2f(a0[0]); xr.y = bf2f(a0[1]); xr.z = bf2f(a0[2]); xr.w = bf2f(a0[3]);
        xz.x = bf2f(a1[0]); xz.y = bf2f(a1[1]); xz.z = bf2f(a1[2]); xz.w = bf2f(a1[3]);
        xn.x = bf2f(a2[0]); xn.y = bf2f(a2[1]); xn.z = bf2f(a2[2]); xn.w = bf2f(a2[3]);
    } else {
        const float* xp = (const float*)xp_t + (size_t)b * G3;
        xr = *(const float4*)&xp[jg];
        xz = *(const float4*)&xp[512 + jg];
        xn = *(const float4*)&xp[1024 + jg];
    }
    float4 br_ = *(const float4*)&b_hh[jg];
    float4 bz_ = *(const float4*)&b_hh[512 + jg];
    float4 bn_ = *(const float4*)&b_hh[1024 + jg];

    float m = mask_t[b];
    float4 hm = *(const float4*)&h_cur[b * HH + jg];
    hm.x *= m; hm.y *= m; hm.z *= m; hm.w *= m;

    float4 h4;
#define GRU1(C) { \
    float r = sigmoidf_(xr.C + hr.C + br_.C); \
    float z = sigmoidf_(xz.C + hz.C + bz_.C); \
    float n = tanhf(xn.C + r * (hn.C + bn_.C)); \
    h4.C = (1.0f - z) * n + z * hm.C; }
    GRU1(x) GRU1(y) GRU1(z) GRU1(w)
#undef GRU1

    *(float4*)&h_nxt[b * HH + jg] = h4;
    *(float4*)&out_t[(size_t)b * HH + jg] = h4;
}

// ---------------- LayerNorm in-place over last dim (512) ----------------
__global__ __launch_bounds__(256) void ln_k(float* __restrict__ y,
                                            const float* __restrict__ lw,
                                            const float* __restrict__ lb) {
    int row = blockIdx.x * 4 + (threadIdx.x >> 6);
    int l = threadIdx.x & 63;
    float* p = y + (size_t)row * HH;
    float4 v0 = *(const float4*)&p[l * 4];
    float4 v1 = *(const float4*)&p[256 + l * 4];
    float s = v0.x + v0.y + v0.z + v0.w + v1.x + v1.y + v1.z + v1.w;
    float q = v0.x*v0.x + v0.y*v0.y + v0.z*v0.z + v0.w*v0.w
            + v1.x*v1.x + v1.y*v1.y + v1.z*v1.z + v1.w*v1.w;
#pragma unroll
    for (int off = 32; off; off >>= 1) {
        s += __shfl_xor(s, off);
        q += __shfl_xor(q, off);
    }
    float mu = s * (1.0f / 512.0f);
    float var = q * (1.0f / 512.0f) - mu * mu;
    float rs = rsqrtf(var + 1e-5f);
    float4 w0 = *(const float4*)&lw[l * 4], w1 = *(const float4*)&lw[256 + l * 4];
    float4 c0 = *(const float4*)&lb[l * 4], c1 = *(const float4*)&lb[256 + l * 4];
    v0.x = (v0.x - mu) * rs * w0.x + c0.x;
    v0.y = (v0.y - mu) * rs * w0.y + c0.y;
    v0.z = (v0.z - mu) * rs * w0.z + c0.z;
    v0.w = (v0.w - mu) * rs * w0.w + c0.w;
    v1.x = (v1.x - mu) * rs * w1.x + c1.x;
    v1.y = (v1.y - mu) * rs * w1.y + c1.y;
    v1.z = (v1.z - mu) * rs * w1.z + c1.z;
    v1.w = (v1.w - mu) * rs * w1.w + c1.w;
    *(float4*)&p[l * 4] = v0;
    *(float4*)&p[256 + l * 4] = v1;
}

extern "C" void kernel_launch(void* const* d_in, const int* in_sizes, int n_in,
                              void* d_out, int out_size, void* d_ws, size_t ws_size,
                              hipStream_t stream) {
    (void)in_sizes; (void)n_in; (void)out_size;
    const float* x     = (const float*)d_in[0];
    const float* h0    = (const float*)d_in[1];   // rnn_states (B,1,H)
    const float* masks = (const float*)d_in[2];   // (T,B,1)
    const float* wih   = (const float*)d_in[3];   // (3H, D)
    const float* whh   = (const float*)d_in[4];   // (3H, H)
    const float* bih   = (const float*)d_in[5];
    const float* bhh   = (const float*)d_in[6];
    const float* lnw   = (const float*)d_in[7];
    const float* lnb   = (const float*)d_in[8];

    float* y  = (float*)d_out;                       // (T,B,H)
    float* hT = y + (size_t)TT * BB * HH;            // (B,1,H)

    char* ws = (char*)d_ws;
    const size_t xp_f32_sz = (size_t)TT * BB * G3 * 4;   // 805 MB
    const size_t xp_bf_sz  = xp_f32_sz / 2;              // 402 MB
    const size_t xbf_sz    = (size_t)TT * BB * DD * 2;   // 134 MB
    const size_t w_sz      = (size_t)G3 * DD * 2;        // 1.5 MB
    const size_t h_sz      = (size_t)BB * HH * 4;        // 1 MB
    const size_t tail      = xbf_sz + 2 * w_sz + 2 * h_sz;
    const bool xpbf = ws_size < xp_f32_sz + tail;        // fallback if ws too small

    size_t off = 0;
    char*   xp   = ws;                 off += xpbf ? xp_bf_sz : xp_f32_sz;
    ushort* xbf  = (ushort*)(ws + off); off += xbf_sz;
    ushort* wihb = (ushort*)(ws + off); off += w_sz;
    ushort* whhb = (ushort*)(ws + off); off += w_sz;
    float*  hA   = (float*)(ws + off);  off += h_sz;
    float*  hB   = (float*)(ws + off);

    // conversions + h0 init
    {
        int n8 = TT * BB * DD / 8;
        conv_f32_bf16<<<(n8 + 255) / 256, 256, 0, stream>>>(x, xbf, n8);
        int nw = G3 * DD / 8;
        conv_f32_bf16<<<(nw + 255) / 256, 256, 0, stream>>>(wih, wihb, nw);
        conv_f32_bf16<<<(nw + 255) / 256, 256, 0, stream>>>(whh, whhb, nw);
        int nh = BB * HH / 4;
        copy_f32<<<(nh + 255) / 256, 256, 0, stream>>>(h0, hA, nh);
    }

    // phase 1: xp
    {
        dim3 gg(G3 / 128, (TT * BB) / 128);   // (12, 1024)
        if (xpbf) gemm_xp<true ><<<gg, 256, 0, stream>>>(xbf, wihb, bih, xp);
        else      gemm_xp<false><<<gg, 256, 0, stream>>>(xbf, wihb, bih, xp);
    }

    // phase 2: sequential scan, ping-pong h
    {
        dim3 gs(HH / 32, BB / 32);   // (16, 16)
        const size_t xp_row = (size_t)BB * G3 * (xpbf ? 2 : 4);
        for (int t = 0; t < TT; ++t) {
            const float* hc = (t & 1) ? hB : hA;
            float*       hn = (t & 1) ? hA : hB;
            const void*  xpt = xp + (size_t)t * xp_row;
            const float* mt  = masks + (size_t)t * BB;
            float*       ot  = y + (size_t)t * BB * HH;
            if (xpbf) gru_step<true ><<<gs, 256, 0, stream>>>(hc, hn, whhb, xpt, mt, bhh, ot);
            else      gru_step<false><<<gs, 256, 0, stream>>>(hc, hn, whhb, xpt, mt, bhh, ot);
        }
    }

    // hT (final h is in hA: t=255 odd writes hA)
    {
        int nh = BB * HH / 4;
        copy_f32<<<(nh + 255) / 256, 256, 0, stream>>>(hA, hT, nh);
    }

    // phase 3: LayerNorm in place on y
    ln_k<<<(TT * BB) / 4, 256, 0, stream>>>(y, lnw, lnb);
}